// Round 10
// baseline (89.411 us; speedup 1.0000x reference)
//
#include <hip/hip_runtime.h>
#include <hip/hip_bf16.h>

#define NTHREADS 256
#define N_ATOMS  1024
#define HIDDEN   64
#define SEGCAP   512     // per-wave queue entries (expected ~65, pad x4)

// 4 atoms per block (B*N/4 = 2048 blocks), one WAVE per atom.  R9 skeleton
// with ONE change (H-LDS probe): neighbors staged as packed float4
// (x,y,z,tsign) -> sweep does ONE ds_read_b128 per neighbor instead of
// 4x ds_read_b32 (2x fewer LDS issue slots, 4x fewer dependent
// load->ballot first-use waits); staging uses ds_write_b128.
__global__ __launch_bounds__(NTHREADS) void LocalFeatureEncoder_40063454937486_kernel(
    const float* __restrict__ pos,    // [B,N,3]
    const int*   __restrict__ types,  // [B,N]
    const float* __restrict__ W1,     // [34,64]
    const float* __restrict__ b1,     // [64]
    const float* __restrict__ W2,     // [64,64]
    const float* __restrict__ b2,     // [64]
    const float* __restrict__ W3,     // [64,64]
    const float* __restrict__ b3,     // [64]
    float*       __restrict__ out)    // [B,N,64]
{
    const int tid  = threadIdx.x;
    const int lane = tid & 63;
    const int wav  = tid >> 6;
    const int a    = blockIdx.x * 4 + wav;   // this wave's atom (b*N + i)
    const int bidx = blockIdx.x >> 8;        // 256 blocks per batch
    const int i    = a & (N_ATOMS - 1);

    __shared__ float4 sp[N_ATOMS];           // packed (x, y, z, tsign)
    __shared__ float  qv[4 * SEGCAP];        // per-wave sign-packed +/-d

    const float* pf   = pos + (size_t)bidx * (N_ATOMS * 3);
    const int*   typb = types + (size_t)bidx * N_ATOMS;

    // ---- stage all 1024 neighbors into packed LDS (once per block) ----
    {
        const float4 p0 = *(const float4*)(pf + tid * 12);
        const float4 p1 = *(const float4*)(pf + tid * 12 + 4);
        const float4 p2 = *(const float4*)(pf + tid * 12 + 8);
        const int4   tv = *(const int4*)(typb + tid * 4);

        const float px[4] = {p0.x, p0.w, p1.z, p2.y};
        const float py[4] = {p0.y, p1.x, p1.w, p2.z};
        const float pz[4] = {p0.z, p1.y, p2.x, p2.w};
        const int   tj[4] = {tv.x, tv.y, tv.z, tv.w};
#pragma unroll
        for (int q = 0; q < 4; ++q) {
            sp[tid * 4 + q] = make_float4(px[q], py[q], pz[q],
                                          (tj[q] == 0) ? 1.0f : -1.0f);
        }
    }
    __syncthreads();

    const float4 self = sp[i];
    const float xi = self.x, yi = self.y, zi = self.z;

    // ---- sweeps + per-wave compaction (sign-packed +/-d) ----
    float* seg = &qv[wav * SEGCAP];
    int base = 0;                            // wave-uniform running count
#pragma unroll
    for (int s = 0; s < N_ATOMS / 64; ++s) {
        const int j = lane + s * 64;
        const float4 nb = sp[j];             // one ds_read_b128
        const float dx = xi - nb.x;
        const float dy = yi - nb.y;
        const float dz = zi - nb.z;
        const float sq = dx * dx + dy * dy + dz * dz;
        const bool pred = (j != i) && (sq < 6.25f);

        const unsigned long long mask = __ballot(pred);
        if (pred) {
            const float d = sqrtf(sq);
            const int idx = base + (int)__popcll(mask & ((1ull << lane) - 1ull));
            seg[idx] = (nb.w > 0.0f) ? d : -d;   // sign encodes species
        }
        base += (int)__popcll(mask);
    }
    // pad to a multiple of 4 with d=100 (zero contribution, finite cutv)
    const int npad = (base + 3) & ~3;
    if (lane < npad - base) seg[base + lane] = 100.0f;
    __syncthreads();                         // queue visible (proven-safe ordering)

    // ---- drain: lane = (slot p = lane>>4, rbf r = lane&15) ----
    float acc0 = 0.0f, acc1 = 0.0f;
    {
        const int   slot = lane >> 4;        // 0..3
        const int   r    = lane & 15;
        const float c    = (float)r * (2.5f / 15.0f);
        for (int e = slot; e < npad; e += 4) {
            const float v   = seg[e];
            const float d   = fabsf(v);
            const float x   = d * 0.4f;      // d / 2.5
            const float x3  = x * x * x;
            const float cutv = 1.0f + x3 * (-10.0f + x * (15.0f - 6.0f * x));
            const float diff = d - c;
            const float ex   = __expf(diff * diff * -36.0f);  // 1/w^2 = 36
            const float m0 = (v > 0.0f) ? cutv : 0.0f;
            const float m1 = (v > 0.0f) ? 0.0f : cutv;
            acc0 += ex * m0;
            acc1 += ex * m1;
        }
    }
    // combine the 4 slots: lanes r, r+16, r+32, r+48
    acc0 += __shfl_xor(acc0, 16, 64);
    acc0 += __shfl_xor(acc0, 32, 64);
    acc1 += __shfl_xor(acc1, 16, 64);
    acc1 += __shfl_xor(acc1, 32, 64);
    // every lane in {r, r+16, r+32, r+48} now holds full env[r][0/1]

    // ---- MLP 34 -> 64 -> 64 -> 64, shuffle-broadcast, all 64 lanes ----
    const int t  = lane;                     // output unit this lane owns
    const int ti = (self.w < 0.0f) ? 1 : 0;  // own atom type (wave-uniform)

    float h1 = b1[t] + W1[ti * HIDDEN + t];  // onehot contribution
#pragma unroll
    for (int r = 0; r < 16; ++r) {
        h1 += __shfl(acc0, r, 64) * W1[(2 + 2 * r + 0) * HIDDEN + t];
        h1 += __shfl(acc1, r, 64) * W1[(2 + 2 * r + 1) * HIDDEN + t];
    }
    h1 = h1 / (1.0f + __expf(-h1));

    float h2 = b2[t];
#pragma unroll
    for (int k = 0; k < HIDDEN; ++k) {
        h2 += __shfl(h1, k, 64) * W2[k * HIDDEN + t];
    }
    h2 = h2 / (1.0f + __expf(-h2));

    float o = b3[t];
#pragma unroll
    for (int k = 0; k < HIDDEN; ++k) {
        o += __shfl(h2, k, 64) * W3[k * HIDDEN + t];
    }
    out[(size_t)a * HIDDEN + t] = o;
}

extern "C" void kernel_launch(void* const* d_in, const int* in_sizes, int n_in,
                              void* d_out, int out_size, void* d_ws, size_t ws_size,
                              hipStream_t stream) {
    const float* pos   = (const float*)d_in[0];
    const int*   types = (const int*)d_in[1];
    const float* W1    = (const float*)d_in[2];
    const float* b1    = (const float*)d_in[3];
    const float* W2    = (const float*)d_in[4];
    const float* b2    = (const float*)d_in[5];
    const float* W3    = (const float*)d_in[6];
    const float* b3    = (const float*)d_in[7];
    float*       out   = (float*)d_out;

    const int BN = in_sizes[1];              // B*N = 8192

    LocalFeatureEncoder_40063454937486_kernel<<<BN / 4, NTHREADS, 0, stream>>>(
        pos, types, W1, b1, W2, b2, W3, b3, out);
}